// Round 9
// baseline (140.152 us; speedup 1.0000x reference)
//
#include <hip/hip_runtime.h>
#include <hip/hip_bf16.h>

// CalcSpixelFeats R9.
// R8 post-mortem: 208->138us; top-5 is now the HARNESS's 268MB d_ws re-poison
// fill (42us @ 79% peak) + input restore (~7us) — a ~50us fixed term in the
// timed window. Controllable: prep ~35 + gather ~45.
// R9: gather was issue-bound (4B/lane loads, ~72 load instrs/thread; L2
// traffic floor is only ~9us). Now uint4 loads, 4 lanes/record (8 ch/lane),
// 128 record-groups x 512 thr -> ~18 iters/thread, 4x fewer load instrs.
// Prep byte-identical to R8 for attribution.

#define CCH  32         // channels, fixed by problem
#define TPB  512        // prep block threads
#define PPB  1024       // pixels per prep block (2 per thread)
#define GTPB 512        // gather block: 4 ch-quad lanes x 128 record groups
#define CAPC 384        // bucket capacity (mean 256, sd 16 -> +8 sigma)
#define RECW 32         // record width in dwords (128 B)
#define KMAX 256

__device__ __forceinline__ unsigned pack_bf16(float a, float b) {
    unsigned ua = __float_as_uint(a);
    unsigned ub = __float_as_uint(b);
    ua = (ua + 0x7FFFu + ((ua >> 16) & 1u)) >> 16;   // RNE
    ub = (ub + 0x7FFFu + ((ub >> 16) & 1u)) >> 16;
    return ua | (ub << 16);
}

__global__ __launch_bounds__(TPB) void spx_prep_kernel(
    const float* __restrict__ pf,      // [B][C][P]
    const float* __restrict__ assoc,   // [B][9][P]
    const int*   __restrict__ idxmap,  // [B][P]
    const int*   __restrict__ nw_p,
    const int*   __restrict__ nh_p,
    int*         __restrict__ cnt,     // [B*K]
    unsigned*    __restrict__ recs,    // [B*K][cap][RECW]
    float*       __restrict__ ovf,     // [B*K][33] overflow accumulator
    int P, int K, int cap, int bpb)    // bpb = P / PPB
{
    __shared__ int hist[KMAX];         // per-block bin counts
    __shared__ int bases[KMAX];        // reserved global base per bin

    const int b   = blockIdx.x / bpb;
    const int blk = blockIdx.x - b * bpb;
    const int tid = threadIdx.x;
    const int p0  = blk * PPB;         // within batch

    for (int i = tid; i < K; i += TPB) hist[i] = 0;
    __syncthreads();

    const int pA = p0 + tid;
    const int pB = p0 + TPB + tid;
    const int*   ix_b = idxmap + (size_t)b * P;
    const float* pf_b = pf     + (size_t)b * CCH * P;
    const float* as_b = assoc  + (size_t)b * 9 * P;

    // local ranks via native LDS int atomics
    const int idxA  = ix_b[pA];
    const int idxB  = ix_b[pB];
    const int rankA = atomicAdd(&hist[idxA], 1);
    const int rankB = atomicAdd(&hist[idxB], 1);

    // bulk loads (independent of the reservation phase; stay in flight)
    unsigned uA[16], uB[16];
#pragma unroll
    for (int c2 = 0; c2 < 16; ++c2) {
        const float a0 = pf_b[(size_t)(2*c2  ) * P + pA];
        const float a1 = pf_b[(size_t)(2*c2+1) * P + pA];
        const float b0 = pf_b[(size_t)(2*c2  ) * P + pB];
        const float b1 = pf_b[(size_t)(2*c2+1) * P + pB];
        uA[c2] = pack_bf16(a0, a1);
        uB[c2] = pack_bf16(b0, b1);
    }
    float wA[9], wB[9];
#pragma unroll
    for (int j = 0; j < 9; ++j) {
        wA[j] = as_b[(size_t)j * P + pA];
        wB[j] = as_b[(size_t)j * P + pB];
    }

    __syncthreads();
    // ONE returning global atomic per (block, bin)
    for (int i = tid; i < K; i += TPB)
        bases[i] = atomicAdd(&cnt[b * K + i], hist[i]);
    __syncthreads();

    const int nw = nw_p[0], nh = nh_p[0];

#pragma unroll
    for (int px = 0; px < 2; ++px) {
        const int idx  = px ? idxB : idxA;
        const int rank = px ? rankB : rankA;
        const unsigned* u = px ? uB : uA;
        const float*    w = px ? wB : wA;
        const int pos = bases[idx] + rank;

        if (pos < cap) {
            uint4* dst = (uint4*)(recs +
                ((size_t)(b * K + idx) * cap + pos) * RECW);
            dst[0] = make_uint4(u[0],  u[1],  u[2],  u[3]);
            dst[1] = make_uint4(u[4],  u[5],  u[6],  u[7]);
            dst[2] = make_uint4(u[8],  u[9],  u[10], u[11]);
            dst[3] = make_uint4(u[12], u[13], u[14], u[15]);
            dst[4] = make_uint4(__float_as_uint(w[0]), __float_as_uint(w[1]),
                                __float_as_uint(w[2]), __float_as_uint(w[3]));
            dst[5] = make_uint4(__float_as_uint(w[4]), __float_as_uint(w[5]),
                                __float_as_uint(w[6]), __float_as_uint(w[7]));
            dst[6] = make_uint4(__float_as_uint(w[8]), 0u, 0u, 0u);
            dst[7] = make_uint4(0u, 0u, 0u, 0u);
        } else {
            // rare overflow: direct scatter with native global fp atomics
            const int iy = idx / nw, ixx = idx - (idx / nw) * nw;
#pragma unroll
            for (int j = 0; j < 9; ++j) {
                const int ty = iy + j / 3 - 1, tx = ixx + j % 3 - 1;
                if (tx >= 0 && tx < nw && ty >= 0 && ty < nh) {
                    float* o = ovf + (size_t)(b * K + ty * nw + tx) * (CCH + 1);
#pragma unroll
                    for (int c2 = 0; c2 < 16; ++c2) {
                        const float f0 = __uint_as_float(u[c2] << 16);
                        const float f1 = __uint_as_float(u[c2] & 0xFFFF0000u);
                        unsafeAtomicAdd(&o[2*c2],     w[j] * f0);
                        unsafeAtomicAdd(&o[2*c2 + 1], w[j] * f1);
                    }
                    unsafeAtomicAdd(&o[CCH], w[j]);
                }
            }
        }
    }
}

// Block owns output bin (b,k). 512 thr = 4 ch-quad lanes x 128 record groups.
// Lane l loads uint4 (= channels 8l..8l+7) per record: 1 dwordx4 + 1 w dword
// per iteration, ~18 iterations total.
__global__ __launch_bounds__(GTPB) void spx_gather_kernel(
    const unsigned* __restrict__ recs,    // [B*K][cap][RECW]
    const int*      __restrict__ cnt,     // [B*K]
    const float*    __restrict__ ovf,     // [B*K][33]
    const int*      __restrict__ nw_p,
    const int*      __restrict__ nh_p,
    float*          __restrict__ out,     // [B][C][K]
    int P, int K, int cap)
{
    __shared__ int   jcnt[9], jsrc[9];
    __shared__ float red[128][CCH + 1];   // 16.9 KB
    __shared__ float red2[8][CCH + 1];

    const int b   = blockIdx.x / K;
    const int k   = blockIdx.x - b * K;
    const int tid = threadIdx.x;
    const int nw  = nw_p[0];
    const int nh  = nh_p[0];
    const int ky  = k / nw;
    const int kx  = k - ky * nw;

    if (tid < 9) {
        const int dy = tid / 3 - 1, dx = tid % 3 - 1;
        const int sy = ky - dy, sx = kx - dx;      // source base bin
        const bool v = (sx >= 0) & (sx < nw) & (sy >= 0) & (sy < nh);
        const int src = v ? (b * K + sy * nw + sx) : 0;
        int c = v ? cnt[src] : 0;
        if (c > cap) c = cap;
        jcnt[tid] = c;
        jsrc[tid] = src;
    }
    __syncthreads();

    const int l = tid & 3;         // ch-quad lane: channels 8l..8l+7
    const int g = tid >> 2;        // record group 0..127

    float a[8] = {0.f, 0.f, 0.f, 0.f, 0.f, 0.f, 0.f, 0.f};
    float wacc = 0.f;

#pragma unroll
    for (int j = 0; j < 9; ++j) {
        const int c = jcnt[j];
        const unsigned* rb = recs + (size_t)jsrc[j] * cap * RECW;
        for (int i = g; i < c; i += 128) {
            const unsigned* r = rb + (size_t)i * RECW;
            const uint4 u = ((const uint4*)r)[l];
            const float w = __uint_as_float(r[16 + j]);
            a[0] += w * __uint_as_float(u.x << 16);
            a[1] += w * __uint_as_float(u.x & 0xFFFF0000u);
            a[2] += w * __uint_as_float(u.y << 16);
            a[3] += w * __uint_as_float(u.y & 0xFFFF0000u);
            a[4] += w * __uint_as_float(u.z << 16);
            a[5] += w * __uint_as_float(u.z & 0xFFFF0000u);
            a[6] += w * __uint_as_float(u.w << 16);
            a[7] += w * __uint_as_float(u.w & 0xFFFF0000u);
            wacc += w;
        }
    }

#pragma unroll
    for (int t = 0; t < 8; ++t) red[g][8 * l + t] = a[t];
    if (l == 0) red[g][CCH] = wacc;
    __syncthreads();

    if (tid < 264) {                       // 33 cols x 8 partials
        const int col = tid >> 3, part = tid & 7;
        float s = 0.f;
#pragma unroll
        for (int r2 = 0; r2 < 16; ++r2) s += red[part * 16 + r2][col];
        red2[part][col] = s;
    }
    __syncthreads();

    if (tid < CCH + 1) {
        float s = 0.f;
#pragma unroll
        for (int r2 = 0; r2 < 8; ++r2) s += red2[r2][tid];
        s += ovf[(size_t)(b * K + k) * (CCH + 1) + tid];
        red2[0][tid] = s;
    }
    __syncthreads();

    if (tid < CCH) {
        const float W = red2[0][CCH];
        out[((size_t)b * CCH + tid) * K + k] =
            (W > 1e-16f) ? (red2[0][tid] / W) : 0.f;
    }
}

extern "C" void kernel_launch(void* const* d_in, const int* in_sizes, int n_in,
                              void* d_out, int out_size, void* d_ws, size_t ws_size,
                              hipStream_t stream) {
    const float* pf     = (const float*)d_in[0];
    const float* assoc  = (const float*)d_in[1];
    const int*   idxmap = (const int*)d_in[2];
    const int*   nw_p   = (const int*)d_in[3];
    const int*   nh_p   = (const int*)d_in[4];
    float* out = (float*)d_out;

    const int BP = in_sizes[2];          // B*P = 262144
    const int B  = 4;                    // fixed by reference setup
    const int P  = BP / B;               // 65536
    const int K  = out_size / (B * CCH); // 256 (== KMAX)

    // workspace: cnt [B*K int] | ovf [B*K*33 f32] | recs [B*K][cap][128B]
    const size_t cnt_bytes = (size_t)B * K * sizeof(int);
    const size_t ovf_bytes = (size_t)B * K * (CCH + 1) * sizeof(float);
    int*      cnt  = (int*)d_ws;
    float*    ovf  = (float*)((char*)d_ws + cnt_bytes);
    unsigned* recs = (unsigned*)((char*)d_ws + cnt_bytes + ovf_bytes);

    size_t avail = (ws_size > cnt_bytes + ovf_bytes)
                       ? (ws_size - cnt_bytes - ovf_bytes) : 0;
    int cap = (int)(avail / ((size_t)B * K * RECW * sizeof(unsigned)));
    if (cap > CAPC) cap = CAPC;
    if (cap < 1) cap = 1;

    hipMemsetAsync(cnt, 0, cnt_bytes + ovf_bytes, stream);  // cnt + ovf = 0

    const int bpb = P / PPB;             // 64 blocks per batch
    spx_prep_kernel<<<B * bpb, TPB, 0, stream>>>(
        pf, assoc, idxmap, nw_p, nh_p, cnt, recs, ovf, P, K, cap, bpb);

    spx_gather_kernel<<<B * K, GTPB, 0, stream>>>(
        recs, cnt, ovf, nw_p, nh_p, out, P, K, cap);
}

// Round 10
// 128.478 us; speedup vs baseline: 1.0909x; 1.0909x over previous
//
#include <hip/hip_runtime.h>
#include <hip/hip_bf16.h>

// CalcSpixelFeats R10.
// R9 post-mortem: gather FETCH=129MB @3TB/s (9x re-read of records, w-line
// dragged 9x for 4B each) — traffic-bound, not issue-bound. Prep ~41us at
// 1 block/CU with 65K returning atomics on 16 packed counter lines.
// R10: (1) counters padded to 1/64B line (parallel LLC serialization),
// (2) 96B records: feats bf16 x32 (64B) + w bf16 x9 (20B) + pad — per-visit
// traffic -25%, (3) prep TPB=1024 (1px/thread, 16 waves/CU).

#define CCH  32         // channels, fixed by problem
#define TPB  1024       // prep block threads (= PPB, 1 px/thread)
#define PPB  1024       // pixels per prep block
#define GTPB 512        // gather block: 4 ch-quad lanes x 128 record groups
#define CAPC 384        // bucket capacity (mean 256, sd 16 -> +8 sigma)
#define RECW 24         // record width in dwords (96 B)
#define CNTS 16         // counter stride in dwords (64 B line)
#define KMAX 256

__device__ __forceinline__ unsigned pack_bf16(float a, float b) {
    unsigned ua = __float_as_uint(a);
    unsigned ub = __float_as_uint(b);
    ua = (ua + 0x7FFFu + ((ua >> 16) & 1u)) >> 16;   // RNE
    ub = (ub + 0x7FFFu + ((ub >> 16) & 1u)) >> 16;
    return ua | (ub << 16);
}

__global__ __launch_bounds__(TPB) void spx_prep_kernel(
    const float* __restrict__ pf,      // [B][C][P]
    const float* __restrict__ assoc,   // [B][9][P]
    const int*   __restrict__ idxmap,  // [B][P]
    const int*   __restrict__ nw_p,
    const int*   __restrict__ nh_p,
    int*         __restrict__ cnt,     // [B*K][CNTS] (padded counters)
    unsigned*    __restrict__ recs,    // [B*K][cap][RECW]
    float*       __restrict__ ovf,     // [B*K][33] overflow accumulator
    int P, int K, int cap, int bpb)    // bpb = P / PPB
{
    __shared__ int hist[KMAX];         // per-block bin counts
    __shared__ int bases[KMAX];        // reserved global base per bin

    const int b   = blockIdx.x / bpb;
    const int blk = blockIdx.x - b * bpb;
    const int tid = threadIdx.x;
    const int p   = blk * PPB + tid;   // within batch (1 px/thread)

    if (tid < KMAX) hist[tid] = 0;
    __syncthreads();

    const int*   ix_b = idxmap + (size_t)b * P;
    const float* pf_b = pf     + (size_t)b * CCH * P;
    const float* as_b = assoc  + (size_t)b * 9 * P;

    const int idx  = ix_b[p];
    const int rank = atomicAdd(&hist[idx], 1);   // native LDS int atomic

    // bulk loads (issue before the reservation barrier; stay in flight)
    unsigned u[16];
#pragma unroll
    for (int c2 = 0; c2 < 16; ++c2) {
        const float f0 = pf_b[(size_t)(2*c2  ) * P + p];
        const float f1 = pf_b[(size_t)(2*c2+1) * P + p];
        u[c2] = pack_bf16(f0, f1);
    }
    float wv[9];
#pragma unroll
    for (int j = 0; j < 9; ++j) wv[j] = as_b[(size_t)j * P + p];

    __syncthreads();
    // one returning global atomic per (block, bin); padded counter lines
    if (tid < KMAX)
        bases[tid] = atomicAdd(&cnt[(b * K + tid) * CNTS], hist[tid]);
    __syncthreads();

    const int pos = bases[idx] + rank;

    if (pos < cap) {
        unsigned* dst = recs + ((size_t)(b * K + idx) * cap + pos) * RECW;
        uint4* d4 = (uint4*)dst;
        d4[0] = make_uint4(u[0],  u[1],  u[2],  u[3]);
        d4[1] = make_uint4(u[4],  u[5],  u[6],  u[7]);
        d4[2] = make_uint4(u[8],  u[9],  u[10], u[11]);
        d4[3] = make_uint4(u[12], u[13], u[14], u[15]);
        d4[4] = make_uint4(pack_bf16(wv[0], wv[1]), pack_bf16(wv[2], wv[3]),
                           pack_bf16(wv[4], wv[5]), pack_bf16(wv[6], wv[7]));
        dst[20] = pack_bf16(wv[8], 0.0f);
    } else {
        // rare overflow: direct scatter with native global fp atomics
        const int nw = nw_p[0], nh = nh_p[0];
        const int iy = idx / nw, ixx = idx - (idx / nw) * nw;
#pragma unroll
        for (int j = 0; j < 9; ++j) {
            const int ty = iy + j / 3 - 1, tx = ixx + j % 3 - 1;
            if (tx >= 0 && tx < nw && ty >= 0 && ty < nh) {
                float* o = ovf + (size_t)(b * K + ty * nw + tx) * (CCH + 1);
#pragma unroll
                for (int c2 = 0; c2 < 16; ++c2) {
                    const float f0 = __uint_as_float(u[c2] << 16);
                    const float f1 = __uint_as_float(u[c2] & 0xFFFF0000u);
                    unsafeAtomicAdd(&o[2*c2],     wv[j] * f0);
                    unsafeAtomicAdd(&o[2*c2 + 1], wv[j] * f1);
                }
                unsafeAtomicAdd(&o[CCH], wv[j]);
            }
        }
    }
}

// Block owns output bin (b,k). 512 thr = 4 ch-quad lanes x 128 record groups.
__global__ __launch_bounds__(GTPB) void spx_gather_kernel(
    const unsigned* __restrict__ recs,    // [B*K][cap][RECW]
    const int*      __restrict__ cnt,     // [B*K][CNTS]
    const float*    __restrict__ ovf,     // [B*K][33]
    const int*      __restrict__ nw_p,
    const int*      __restrict__ nh_p,
    float*          __restrict__ out,     // [B][C][K]
    int P, int K, int cap)
{
    __shared__ int   jcnt[9], jsrc[9];
    __shared__ float red[128][CCH + 1];   // 16.9 KB
    __shared__ float red2[8][CCH + 1];

    const int b   = blockIdx.x / K;
    const int k   = blockIdx.x - b * K;
    const int tid = threadIdx.x;
    const int nw  = nw_p[0];
    const int nh  = nh_p[0];
    const int ky  = k / nw;
    const int kx  = k - ky * nw;

    if (tid < 9) {
        const int dy = tid / 3 - 1, dx = tid % 3 - 1;
        const int sy = ky - dy, sx = kx - dx;      // source base bin
        const bool v = (sx >= 0) & (sx < nw) & (sy >= 0) & (sy < nh);
        const int src = v ? (b * K + sy * nw + sx) : 0;
        int c = v ? cnt[src * CNTS] : 0;
        if (c > cap) c = cap;
        jcnt[tid] = c;
        jsrc[tid] = src;
    }
    __syncthreads();

    const int l = tid & 3;         // ch-quad lane: channels 8l..8l+7
    const int g = tid >> 2;        // record group 0..127

    float a[8] = {0.f, 0.f, 0.f, 0.f, 0.f, 0.f, 0.f, 0.f};
    float wacc = 0.f;

#pragma unroll
    for (int j = 0; j < 9; ++j) {
        const int c = jcnt[j];
        const unsigned* rb = recs + (size_t)jsrc[j] * cap * RECW;
        for (int i = g; i < c; i += 128) {
            const unsigned* r = rb + (size_t)i * RECW;
            const uint4 u = *(const uint4*)(r + 4 * l);
            const unsigned wp = r[16 + (j >> 1)];
            const float w = (j & 1) ? __uint_as_float(wp & 0xFFFF0000u)
                                    : __uint_as_float(wp << 16);
            a[0] += w * __uint_as_float(u.x << 16);
            a[1] += w * __uint_as_float(u.x & 0xFFFF0000u);
            a[2] += w * __uint_as_float(u.y << 16);
            a[3] += w * __uint_as_float(u.y & 0xFFFF0000u);
            a[4] += w * __uint_as_float(u.z << 16);
            a[5] += w * __uint_as_float(u.z & 0xFFFF0000u);
            a[6] += w * __uint_as_float(u.w << 16);
            a[7] += w * __uint_as_float(u.w & 0xFFFF0000u);
            wacc += w;
        }
    }

#pragma unroll
    for (int t = 0; t < 8; ++t) red[g][8 * l + t] = a[t];
    if (l == 0) red[g][CCH] = wacc;
    __syncthreads();

    if (tid < 264) {                       // 33 cols x 8 partials
        const int col = tid >> 3, part = tid & 7;
        float s = 0.f;
#pragma unroll
        for (int r2 = 0; r2 < 16; ++r2) s += red[part * 16 + r2][col];
        red2[part][col] = s;
    }
    __syncthreads();

    if (tid < CCH + 1) {
        float s = 0.f;
#pragma unroll
        for (int r2 = 0; r2 < 8; ++r2) s += red2[r2][tid];
        s += ovf[(size_t)(b * K + k) * (CCH + 1) + tid];
        red2[0][tid] = s;
    }
    __syncthreads();

    if (tid < CCH) {
        const float W = red2[0][CCH];
        out[((size_t)b * CCH + tid) * K + k] =
            (W > 1e-16f) ? (red2[0][tid] / W) : 0.f;
    }
}

extern "C" void kernel_launch(void* const* d_in, const int* in_sizes, int n_in,
                              void* d_out, int out_size, void* d_ws, size_t ws_size,
                              hipStream_t stream) {
    const float* pf     = (const float*)d_in[0];
    const float* assoc  = (const float*)d_in[1];
    const int*   idxmap = (const int*)d_in[2];
    const int*   nw_p   = (const int*)d_in[3];
    const int*   nh_p   = (const int*)d_in[4];
    float* out = (float*)d_out;

    const int BP = in_sizes[2];          // B*P = 262144
    const int B  = 4;                    // fixed by reference setup
    const int P  = BP / B;               // 65536
    const int K  = out_size / (B * CCH); // 256 (== KMAX)

    // workspace: cnt [B*K][CNTS] | ovf [B*K*33 f32] | recs [B*K][cap][96B]
    const size_t cnt_bytes = (size_t)B * K * CNTS * sizeof(int);   // 64 KB
    const size_t ovf_bytes = (size_t)B * K * (CCH + 1) * sizeof(float);
    int*      cnt  = (int*)d_ws;
    float*    ovf  = (float*)((char*)d_ws + cnt_bytes);
    unsigned* recs = (unsigned*)((char*)d_ws + cnt_bytes + ovf_bytes);

    size_t avail = (ws_size > cnt_bytes + ovf_bytes)
                       ? (ws_size - cnt_bytes - ovf_bytes) : 0;
    int cap = (int)(avail / ((size_t)B * K * RECW * sizeof(unsigned)));
    if (cap > CAPC) cap = CAPC;
    if (cap < 1) cap = 1;

    hipMemsetAsync(cnt, 0, cnt_bytes + ovf_bytes, stream);  // cnt + ovf = 0

    const int bpb = P / PPB;             // 64 blocks per batch
    spx_prep_kernel<<<B * bpb, TPB, 0, stream>>>(
        pf, assoc, idxmap, nw_p, nh_p, cnt, recs, ovf, P, K, cap, bpb);

    spx_gather_kernel<<<B * K, GTPB, 0, stream>>>(
        recs, cnt, ovf, nw_p, nh_p, out, P, K, cap);
}

// Round 11
// 112.375 us; speedup vs baseline: 1.2472x; 1.1433x over previous
//
#include <hip/hip_runtime.h>
#include <hip/hip_bf16.h>

// CalcSpixelFeats R11.
// R10 post-mortem: prep+gather ~78us controllable; gather still re-reads the
// 25MB record array 9x (once per target bin) = ~97MB traffic @ ~3TB/s.
// R11: source-scan. Block per SOURCE bucket streams records ONCE, accumulates
// all 9 target partials in registers (acc[9][2]/thread), LDS-reduce, writes
// partial[(b,s)][9][33] (1.2MB). New finalize: block per target bin sums the
// 9 valid partial[k-dj][j] vectors + ovf, normalizes, transposed write.
// Prep unchanged from R10.

#define CCH  32         // channels, fixed by problem
#define TPB  1024       // prep block threads (= PPB, 1 px/thread)
#define PPB  1024       // pixels per prep block
#define STPB 512        // scan block: 16 ch-pair lanes x 32 record groups
#define CAPC 384        // bucket capacity (mean 256, sd 16 -> +8 sigma)
#define RECW 24         // record width in dwords (96 B)
#define CNTS 16         // counter stride in dwords (64 B line)
#define KMAX 256

__device__ __forceinline__ unsigned pack_bf16(float a, float b) {
    unsigned ua = __float_as_uint(a);
    unsigned ub = __float_as_uint(b);
    ua = (ua + 0x7FFFu + ((ua >> 16) & 1u)) >> 16;   // RNE
    ub = (ub + 0x7FFFu + ((ub >> 16) & 1u)) >> 16;
    return ua | (ub << 16);
}
__device__ __forceinline__ float bf_lo(unsigned u) {
    return __uint_as_float(u << 16);
}
__device__ __forceinline__ float bf_hi(unsigned u) {
    return __uint_as_float(u & 0xFFFF0000u);
}

__global__ __launch_bounds__(TPB) void spx_prep_kernel(
    const float* __restrict__ pf,      // [B][C][P]
    const float* __restrict__ assoc,   // [B][9][P]
    const int*   __restrict__ idxmap,  // [B][P]
    const int*   __restrict__ nw_p,
    const int*   __restrict__ nh_p,
    int*         __restrict__ cnt,     // [B*K][CNTS] (padded counters)
    unsigned*    __restrict__ recs,    // [B*K][cap][RECW]
    float*       __restrict__ ovf,     // [B*K][33] overflow accumulator
    int P, int K, int cap, int bpb)    // bpb = P / PPB
{
    __shared__ int hist[KMAX];         // per-block bin counts
    __shared__ int bases[KMAX];        // reserved global base per bin

    const int b   = blockIdx.x / bpb;
    const int blk = blockIdx.x - b * bpb;
    const int tid = threadIdx.x;
    const int p   = blk * PPB + tid;   // within batch (1 px/thread)

    if (tid < KMAX) hist[tid] = 0;
    __syncthreads();

    const int*   ix_b = idxmap + (size_t)b * P;
    const float* pf_b = pf     + (size_t)b * CCH * P;
    const float* as_b = assoc  + (size_t)b * 9 * P;

    const int idx  = ix_b[p];
    const int rank = atomicAdd(&hist[idx], 1);   // native LDS int atomic

    unsigned u[16];
#pragma unroll
    for (int c2 = 0; c2 < 16; ++c2) {
        const float f0 = pf_b[(size_t)(2*c2  ) * P + p];
        const float f1 = pf_b[(size_t)(2*c2+1) * P + p];
        u[c2] = pack_bf16(f0, f1);
    }
    float wv[9];
#pragma unroll
    for (int j = 0; j < 9; ++j) wv[j] = as_b[(size_t)j * P + p];

    __syncthreads();
    if (tid < KMAX)
        bases[tid] = atomicAdd(&cnt[(b * K + tid) * CNTS], hist[tid]);
    __syncthreads();

    const int pos = bases[idx] + rank;

    if (pos < cap) {
        unsigned* dst = recs + ((size_t)(b * K + idx) * cap + pos) * RECW;
        uint4* d4 = (uint4*)dst;
        d4[0] = make_uint4(u[0],  u[1],  u[2],  u[3]);
        d4[1] = make_uint4(u[4],  u[5],  u[6],  u[7]);
        d4[2] = make_uint4(u[8],  u[9],  u[10], u[11]);
        d4[3] = make_uint4(u[12], u[13], u[14], u[15]);
        d4[4] = make_uint4(pack_bf16(wv[0], wv[1]), pack_bf16(wv[2], wv[3]),
                           pack_bf16(wv[4], wv[5]), pack_bf16(wv[6], wv[7]));
        dst[20] = pack_bf16(wv[8], 0.0f);
    } else {
        // rare overflow: direct scatter with native global fp atomics
        const int nw = nw_p[0], nh = nh_p[0];
        const int iy = idx / nw, ixx = idx - (idx / nw) * nw;
#pragma unroll
        for (int j = 0; j < 9; ++j) {
            const int ty = iy + j / 3 - 1, tx = ixx + j % 3 - 1;
            if (tx >= 0 && tx < nw && ty >= 0 && ty < nh) {
                float* o = ovf + (size_t)(b * K + ty * nw + tx) * (CCH + 1);
#pragma unroll
                for (int c2 = 0; c2 < 16; ++c2) {
                    unsafeAtomicAdd(&o[2*c2],     wv[j] * bf_lo(u[c2]));
                    unsafeAtomicAdd(&o[2*c2 + 1], wv[j] * bf_hi(u[c2]));
                }
                unsafeAtomicAdd(&o[CCH], wv[j]);
            }
        }
    }
}

// Block per SOURCE bucket (b,s): stream records once, accumulate 9 target
// partials in registers, LDS-reduce, write partial[(b,s)][9][CCH+1].
__global__ __launch_bounds__(STPB) void spx_scan_kernel(
    const unsigned* __restrict__ recs,    // [B*K][cap][RECW]
    const int*      __restrict__ cnt,     // [B*K][CNTS]
    float*          __restrict__ partial, // [B*K][9][CCH+1]
    int K, int cap)
{
    __shared__ float red[32][9][CCH + 1];   // 38 KB

    const int bs  = blockIdx.x;             // b*K + s
    const int tid = threadIdx.x;
    const int c2  = tid & 15;               // channel pair
    const int g   = tid >> 4;               // record group 0..31

    int c = cnt[bs * CNTS];
    if (c > cap) c = cap;
    const unsigned* rb = recs + (size_t)bs * cap * RECW;

    float a[9][2];
    float wa = 0.f;
#pragma unroll
    for (int j = 0; j < 9; ++j) { a[j][0] = 0.f; a[j][1] = 0.f; }

    for (int i = g; i < c; i += 32) {
        const unsigned* r = rb + (size_t)i * RECW;
        const unsigned uf  = r[c2];
        const float f0 = bf_lo(uf), f1 = bf_hi(uf);
        const unsigned wp0 = r[16], wp1 = r[17], wp2 = r[18],
                       wp3 = r[19], wp4 = r[20];
        const float w[9] = { bf_lo(wp0), bf_hi(wp0), bf_lo(wp1), bf_hi(wp1),
                             bf_lo(wp2), bf_hi(wp2), bf_lo(wp3), bf_hi(wp3),
                             bf_lo(wp4) };
#pragma unroll
        for (int j = 0; j < 9; ++j) {
            a[j][0] += w[j] * f0;
            a[j][1] += w[j] * f1;
        }
        wa += w[0] + w[1] + w[2] + w[3] + w[4] + w[5] + w[6] + w[7] + w[8];
    }

    // wa holds sum over ALL j; we need per-j wsum. Recompute per-j wsum via
    // the same trick as a[]: store per-j partial w sums. Use a[j] path:
    // (store w-sum per j in red[...][CCH] -> need per-thread per-j wsum)
    // -> accumulate per-j w in registers too:
    (void)wa;

    // per-j w sums (only c2==0 lane's copy is used)
    float ws[9];
#pragma unroll
    for (int j = 0; j < 9; ++j) ws[j] = 0.f;
    if (c2 == 0) {
        for (int i = g; i < c; i += 32) {
            const unsigned* r = rb + (size_t)i * RECW;
            const unsigned wp0 = r[16], wp1 = r[17], wp2 = r[18],
                           wp3 = r[19], wp4 = r[20];
            ws[0] += bf_lo(wp0); ws[1] += bf_hi(wp0);
            ws[2] += bf_lo(wp1); ws[3] += bf_hi(wp1);
            ws[4] += bf_lo(wp2); ws[5] += bf_hi(wp2);
            ws[6] += bf_lo(wp3); ws[7] += bf_hi(wp3);
            ws[8] += bf_lo(wp4);
        }
    }

#pragma unroll
    for (int j = 0; j < 9; ++j) {
        red[g][j][2 * c2]     = a[j][0];
        red[g][j][2 * c2 + 1] = a[j][1];
    }
    if (c2 == 0) {
#pragma unroll
        for (int j = 0; j < 9; ++j) red[g][j][CCH] = ws[j];
    }
    __syncthreads();

    float* pout = partial + (size_t)bs * 9 * (CCH + 1);
    for (int col = tid; col < 9 * (CCH + 1); col += STPB) {
        const int j  = col / (CCH + 1);
        const int cc = col - j * (CCH + 1);
        float s = 0.f;
#pragma unroll
        for (int g2 = 0; g2 < 32; ++g2) s += red[g2][j][cc];
        pout[col] = s;
    }
}

// Block per target bin (b,k): sum 9 valid partial[k-dj][j] + ovf, normalize.
__global__ __launch_bounds__(64) void spx_finalize_kernel(
    const float* __restrict__ partial,  // [B*K][9][CCH+1]
    const float* __restrict__ ovf,      // [B*K][CCH+1]
    const int*   __restrict__ nw_p,
    const int*   __restrict__ nh_p,
    float*       __restrict__ out,      // [B][C][K]
    int K)
{
    __shared__ float F[CCH + 1];

    const int b   = blockIdx.x / K;
    const int k   = blockIdx.x - b * K;
    const int tid = threadIdx.x;
    const int nw  = nw_p[0];
    const int nh  = nh_p[0];
    const int ky  = k / nw;
    const int kx  = k - ky * nw;

    if (tid < CCH + 1) {
        float s = ovf[(size_t)(b * K + k) * (CCH + 1) + tid];
#pragma unroll
        for (int j = 0; j < 9; ++j) {
            const int dy = j / 3 - 1, dx = j % 3 - 1;
            const int sy = ky - dy, sx = kx - dx;
            if (sx >= 0 && sx < nw && sy >= 0 && sy < nh) {
                s += partial[((size_t)(b * K + sy * nw + sx) * 9 + j)
                             * (CCH + 1) + tid];
            }
        }
        F[tid] = s;
    }
    __syncthreads();

    if (tid < CCH) {
        const float W = F[CCH];
        out[((size_t)b * CCH + tid) * K + k] =
            (W > 1e-16f) ? (F[tid] / W) : 0.f;
    }
}

extern "C" void kernel_launch(void* const* d_in, const int* in_sizes, int n_in,
                              void* d_out, int out_size, void* d_ws, size_t ws_size,
                              hipStream_t stream) {
    const float* pf     = (const float*)d_in[0];
    const float* assoc  = (const float*)d_in[1];
    const int*   idxmap = (const int*)d_in[2];
    const int*   nw_p   = (const int*)d_in[3];
    const int*   nh_p   = (const int*)d_in[4];
    float* out = (float*)d_out;

    const int BP = in_sizes[2];          // B*P = 262144
    const int B  = 4;                    // fixed by reference setup
    const int P  = BP / B;               // 65536
    const int K  = out_size / (B * CCH); // 256 (== KMAX)

    // ws: cnt [B*K][CNTS] | ovf [B*K][33] | partial [B*K][9][33] | recs
    const size_t cnt_bytes  = (size_t)B * K * CNTS * sizeof(int);
    const size_t ovf_bytes  = (size_t)B * K * (CCH + 1) * sizeof(float);
    const size_t part_bytes = (size_t)B * K * 9 * (CCH + 1) * sizeof(float);
    int*      cnt     = (int*)d_ws;
    float*    ovf     = (float*)((char*)d_ws + cnt_bytes);
    float*    partial = (float*)((char*)d_ws + cnt_bytes + ovf_bytes);
    unsigned* recs    = (unsigned*)((char*)d_ws + cnt_bytes + ovf_bytes
                                    + part_bytes);

    size_t used = cnt_bytes + ovf_bytes + part_bytes;
    size_t avail = (ws_size > used) ? (ws_size - used) : 0;
    int cap = (int)(avail / ((size_t)B * K * RECW * sizeof(unsigned)));
    if (cap > CAPC) cap = CAPC;
    if (cap < 1) cap = 1;

    hipMemsetAsync(cnt, 0, cnt_bytes + ovf_bytes, stream);  // cnt + ovf = 0

    const int bpb = P / PPB;             // 64 blocks per batch
    spx_prep_kernel<<<B * bpb, TPB, 0, stream>>>(
        pf, assoc, idxmap, nw_p, nh_p, cnt, recs, ovf, P, K, cap, bpb);

    spx_scan_kernel<<<B * K, STPB, 0, stream>>>(recs, cnt, partial, K, cap);

    spx_finalize_kernel<<<B * K, 64, 0, stream>>>(
        partial, ovf, nw_p, nh_p, out, K);
}